// Round 4
// baseline (1167.348 us; speedup 1.0000x reference)
//
#include <hip/hip_runtime.h>
#include <math.h>

// FSQ: h = LayerNorm(x); logits = h @ W^T (n=8); q = round(4*tanh(logits))
// rows = 65536, D = 1024. Memory-bound (256 MiB read), roofline ~43 us.
// Fast path: f64 truth, wave-per-row, register-resident W. Rows with 4*tanh
// within 1e-3 of a rounding boundary (~400) take a fixup that replicates
// numpy-f32 semantics bit-exactly:
//   mean/var : pairwise sum, 128-blocks, 8 scalar accumulators, fixed trees
//   einsum   : SSE3 baseline c_einsum dot — width 4, mul+add (no fma),
//              k-unroll x4 serpentine (j=3..0), hadd finale (v0+v1)+(v2+v3)
//   h        : strict f32 ((x-mu)*rstd)*gamma+beta, rstd=1/sqrtf(var+1e-5f)
//   tanh     : f64 tanh of the exact logit32 (numpy tanhf <=2.5ulp agrees
//              outside a ~6e-7 ambiguity band)

#define NROWS 65536
#define DMODEL 1024
#define NL 8
#define NBLOCKS 512
#define TPB 256
#define NWAVES (NBLOCKS * TPB / 64)   // 2048 -> 32 rows/wave
#define MARGIN 1e-3

// Reduce-scatter 8 doubles across 64 lanes.
// After: every lane holds total of a[n] with n = 4*bit5 + 2*bit4 + 1*bit3.
__device__ __forceinline__ double reduce_scatter8(double a[8], int lane) {
#pragma unroll
    for (int i = 0; i < 4; ++i) {
        double snd = (lane & 32) ? a[i] : a[i + 4];
        double rcv = __shfl_xor(snd, 32, 64);
        double kp  = (lane & 32) ? a[i + 4] : a[i];
        a[i] = kp + rcv;
    }
#pragma unroll
    for (int i = 0; i < 2; ++i) {
        double snd = (lane & 16) ? a[i] : a[i + 2];
        double rcv = __shfl_xor(snd, 16, 64);
        double kp  = (lane & 16) ? a[i + 2] : a[i];
        a[i] = kp + rcv;
    }
    {
        double snd = (lane & 8) ? a[0] : a[1];
        double rcv = __shfl_xor(snd, 8, 64);
        double kp  = (lane & 8) ? a[1] : a[0];
        a[0] = kp + rcv;
    }
    double v = a[0];
    v += __shfl_xor(v, 4, 64);
    v += __shfl_xor(v, 2, 64);
    v += __shfl_xor(v, 1, 64);
    return v;
}

// numpy pairwise_sum over 1024 contiguous f32 in LDS, bit-exact:
// 4 recursion levels -> 8 blocks of 128; per block 8 accumulators r[j],
// r[j] = x[j]; r[j] += x[8i+j] (i=1..15); tree ((r0+r1)+(r2+r3))+((r4+r5)+(r6+r7));
// block sums combined ((s0+s1)+(s2+s3))+((s4+s5)+(s6+s7)).
// Lane L = 8*b + j owns accumulator j of block b; butterfly masks 1,2,4,8,16,32
// reproduce both trees bit-exactly (fl(a+b)==fl(b+a) => all lanes identical).
__device__ __forceinline__ float np_pairwise_sum_sq(const float* xr, int lane,
                                                    float mu, int do_sq) {
    const int b = lane >> 3, j = lane & 7;
    const float* xb = xr + 128 * b;
    float r;
    if (do_sq) {
        float t = __fsub_rn(xb[j], mu);
        r = __fmul_rn(t, t);
        for (int i = 8; i < 128; i += 8) {
            float u = __fsub_rn(xb[i + j], mu);
            r = __fadd_rn(r, __fmul_rn(u, u));
        }
    } else {
        r = xb[j];
        for (int i = 8; i < 128; i += 8)
            r = __fadd_rn(r, xb[i + j]);
    }
    r = __fadd_rn(r, __shfl_xor(r, 1, 64));
    r = __fadd_rn(r, __shfl_xor(r, 2, 64));
    r = __fadd_rn(r, __shfl_xor(r, 4, 64));
    r = __fadd_rn(r, __shfl_xor(r, 8, 64));
    r = __fadd_rn(r, __shfl_xor(r, 16, 64));
    r = __fadd_rn(r, __shfl_xor(r, 32, 64));
    return r;   // identical on all 64 lanes
}

__global__ __launch_bounds__(TPB, 2)
void fsq_kernel(const float* __restrict__ x,
                const float* __restrict__ gamma,
                const float* __restrict__ beta,
                const float* __restrict__ W,
                float* __restrict__ out)
{
    __shared__ float xbuf[TPB / 64][DMODEL];   // 16 KiB: staged x row per wave

    const int lane = threadIdx.x & 63;
    const int wv   = threadIdx.x >> 6;
    const int wid  = (blockIdx.x * TPB + threadIdx.x) >> 6;

    // output column this lane's reduce-scatter group owns
    const int nidx = ((lane >> 5) & 1) * 4 + ((lane >> 4) & 1) * 2 + ((lane >> 3) & 1);

    // ------------- prologue: register-resident W, gamma, beta; S2/S3 -------------
    float4 wreg[NL][4];
    float4 greg[4];
    float4 breg[4];
#pragma unroll
    for (int c = 0; c < 4; ++c) {
        const int d = c * 256 + lane * 4;
        greg[c] = *reinterpret_cast<const float4*>(gamma + d);
        breg[c] = *reinterpret_cast<const float4*>(beta + d);
#pragma unroll
        for (int n = 0; n < NL; ++n)
            wreg[n][c] = *reinterpret_cast<const float4*>(W + n * DMODEL + d);
    }

    double s2p[NL], s3p[NL];
#pragma unroll
    for (int n = 0; n < NL; ++n) { s2p[n] = 0.0; s3p[n] = 0.0; }
#pragma unroll
    for (int c = 0; c < 4; ++c) {
        const double g0 = (double)greg[c].x, g1 = (double)greg[c].y,
                     g2 = (double)greg[c].z, g3 = (double)greg[c].w;
        const double b0 = (double)breg[c].x, b1 = (double)breg[c].y,
                     b2 = (double)breg[c].z, b3 = (double)breg[c].w;
#pragma unroll
        for (int n = 0; n < NL; ++n) {
            const double w0 = (double)wreg[n][c].x, w1 = (double)wreg[n][c].y,
                         w2 = (double)wreg[n][c].z, w3 = (double)wreg[n][c].w;
            s2p[n] = fma(g0, w0, s2p[n]); s2p[n] = fma(g1, w1, s2p[n]);
            s2p[n] = fma(g2, w2, s2p[n]); s2p[n] = fma(g3, w3, s2p[n]);
            s3p[n] = fma(b0, w0, s3p[n]); s3p[n] = fma(b1, w1, s3p[n]);
            s3p[n] = fma(b2, w2, s3p[n]); s3p[n] = fma(b3, w3, s3p[n]);
        }
    }
    const double S2 = reduce_scatter8(s2p, lane);
    const double S3 = reduce_scatter8(s3p, lane);

    // ---------------- row loop with x prefetch ----------------
    int r = wid;
    float4 xa[4];
#pragma unroll
    for (int c = 0; c < 4; ++c)
        xa[c] = *reinterpret_cast<const float4*>(x + (size_t)r * DMODEL + c * 256 + lane * 4);

    while (r < NROWS) {
        const int rn = r + NWAVES;
        const int rp = (rn < NROWS) ? rn : r;
        float4 xb[4];
#pragma unroll
        for (int c = 0; c < 4; ++c)
            xb[c] = *reinterpret_cast<const float4*>(x + (size_t)rp * DMODEL + c * 256 + lane * 4);

        // --- per-lane accumulate (fp64 truth path) ---
        double s = 0.0, qq = 0.0;
        double A[NL];
#pragma unroll
        for (int n = 0; n < NL; ++n) A[n] = 0.0;

#pragma unroll
        for (int c = 0; c < 4; ++c) {
            const double x0 = (double)xa[c].x, x1 = (double)xa[c].y,
                         x2 = (double)xa[c].z, x3 = (double)xa[c].w;
            s += x0 + x1 + x2 + x3;
            qq = fma(x0, x0, qq); qq = fma(x1, x1, qq);
            qq = fma(x2, x2, qq); qq = fma(x3, x3, qq);
            const double g0 = x0 * (double)greg[c].x, g1 = x1 * (double)greg[c].y,
                         g2 = x2 * (double)greg[c].z, g3 = x3 * (double)greg[c].w;
#pragma unroll
            for (int n = 0; n < NL; ++n) {
                A[n] = fma(g0, (double)wreg[n][c].x, A[n]);
                A[n] = fma(g1, (double)wreg[n][c].y, A[n]);
                A[n] = fma(g2, (double)wreg[n][c].z, A[n]);
                A[n] = fma(g3, (double)wreg[n][c].w, A[n]);
            }
        }

#pragma unroll
        for (int m = 32; m >= 1; m >>= 1) {
            s  += __shfl_xor(s,  m, 64);
            qq += __shfl_xor(qq, m, 64);
        }
        const double S1 = reduce_scatter8(A, lane);

        const double mu   = s  * (1.0 / 1024.0);
        const double var  = qq * (1.0 / 1024.0) - mu * mu;
        const double rstd = 1.0 / sqrt(var + 1e-5);
        const double logit = rstd * (S1 - mu * S2) + S3;
        const double b4t = 4.0 * tanh(logit);

        const double frac  = b4t - floor(b4t);
        const double delta = fabs(frac - 0.5);
        const unsigned long long near_mask = __ballot(delta < MARGIN);

        if (near_mask == 0ull) {
            if ((lane & 7) == 0)
                out[(size_t)r * NL + nidx] = (float)rint(b4t);
        } else {
            // ======== fixup: bit-exact numpy-f32 replication ========
            float* xr = &xbuf[wv][0];
#pragma unroll
            for (int c = 0; c < 4; ++c)
                *reinterpret_cast<float4*>(xr + c * 256 + lane * 4) = xa[c];
            __threadfence_block();   // drain ds_writes before cross-lane reads

            // mean: pairwise f32, /1024 exact
            const float sum32 = np_pairwise_sum_sq(xr, lane, 0.0f, 0);
            const float mu32  = __fmul_rn(sum32, 0.0009765625f);
            // var: pairwise f32 over (x-mu)^2, /1024 exact
            const float sq32  = np_pairwise_sum_sq(xr, lane, mu32, 1);
            const float var32 = __fmul_rn(sq32, 0.0009765625f);
            const float rstd32 = __fdiv_rn(1.0f, __fsqrt_rn(__fadd_rn(var32, 1e-5f)));

            // einsum dot, SSE3 baseline c_einsum: width 4, no fma,
            // 16 elems/iter, serpentine j=3..0, finale (v0+v1)+(v2+v3).
            if (lane < 32) {
                const int n = lane >> 2, v = lane & 3;
                const float* Wn = W + n * DMODEL;
                float vacc = 0.0f;
                for (int i = 0; i < DMODEL; i += 16) {
#pragma unroll
                    for (int j = 3; j >= 0; --j) {
                        const int e = i + 4 * j + v;
                        const float t1 = __fsub_rn(xr[e], mu32);
                        const float t2 = __fmul_rn(t1, rstd32);
                        const float t3 = __fmul_rn(t2, gamma[e]);
                        const float h  = __fadd_rn(t3, beta[e]);
                        vacc = __fadd_rn(__fmul_rn(h, Wn[e]), vacc);
                    }
                }
                float s01 = __fadd_rn(vacc, __shfl_xor(vacc, 1, 64));
                float lg  = __fadd_rn(s01,  __shfl_xor(s01, 2, 64));
                if (v == 0) {
                    const double y = 4.0 * tanh((double)lg);
                    out[(size_t)r * NL + n] = (float)rint(y);
                }
            }
        }

#pragma unroll
        for (int c = 0; c < 4; ++c) xa[c] = xb[c];
        r = rn;
    }
}

extern "C" void kernel_launch(void* const* d_in, const int* in_sizes, int n_in,
                              void* d_out, int out_size, void* d_ws, size_t ws_size,
                              hipStream_t stream) {
    const float* regrs = (const float*)d_in[0];
    const float* gamma = (const float*)d_in[1];
    const float* beta  = (const float*)d_in[2];
    const float* W     = (const float*)d_in[3];
    float* out = (float*)d_out;
    (void)in_sizes; (void)n_in; (void)out_size; (void)d_ws; (void)ws_size;

    fsq_kernel<<<NBLOCKS, TPB, 0, stream>>>(regrs, gamma, beta, W, out);
}